// Round 2
// baseline (300.367 us; speedup 1.0000x reference)
//
#include <hip/hip_runtime.h>

#define MROWS   16384
#define NCOLS   256
#define NV4     (NCOLS / 4)    // 64 float4 per row
#define CHUNKS  8              // column chunks: col>>11, 2048 dense rows = 2 MB each
#define CSHIFT  11
#define NB      (MROWS * CHUNKS)   // 131072 buckets

// ---------------- K2: histogram of (row, col-chunk) keys ----------------
__global__ void k_hist(const int* __restrict__ rows, const int* __restrict__ cols,
                       int* __restrict__ cnt, int nnz) {
    int t = blockIdx.x * blockDim.x + threadIdx.x;
    if (t < nnz) {
        int key = (rows[t] << 3) | (cols[t] >> CSHIFT);
        atomicAdd(&cnt[key], 1);
    }
}

// ---------------- K3: exclusive scan of NB counts -> bstart, cursor ----------------
__global__ __launch_bounds__(1024) void k_scan(const int* __restrict__ cnt,
                                               int* __restrict__ bstart,
                                               int* __restrict__ cursor) {
    __shared__ int partial[1024];
    const int tid = threadIdx.x;
    const int PER = NB / 1024;  // 128
    // pass 1: per-thread sum
    int sum = 0;
    for (int k = 0; k < PER; ++k) sum += cnt[tid * PER + k];
    partial[tid] = sum;
    __syncthreads();
    // Hillis-Steele inclusive scan over 1024 partials
    for (int off = 1; off < 1024; off <<= 1) {
        int v = 0;
        if (tid >= off) v = partial[tid - off];
        __syncthreads();
        if (tid >= off) partial[tid] += v;
        __syncthreads();
    }
    int run = (tid == 0) ? 0 : partial[tid - 1];
    // pass 2: re-read counts, emit exclusive prefix
    for (int k = 0; k < PER; ++k) {
        int c = cnt[tid * PER + k];
        bstart[tid * PER + k] = run;
        cursor[tid * PER + k] = run;
        run += c;
    }
    if (tid == 1023) bstart[NB] = run;  // == total nnz
}

// ---------------- K4: scatter nnz into (row,chunk)-sorted order, packed 8B ----------------
__global__ void k_scatter(const float* __restrict__ values, const int* __restrict__ rows,
                          const int* __restrict__ cols, int* __restrict__ cursor,
                          int2* __restrict__ pack, int nnz) {
    int t = blockIdx.x * blockDim.x + threadIdx.x;
    if (t < nnz) {
        int c   = cols[t];
        int key = (rows[t] << 3) | (c >> CSHIFT);
        int pos = atomicAdd(&cursor[key], 1);
        pack[pos] = make_int2(c, __float_as_int(values[t]));
    }
}

// ---------------- K5: per-row gather-accumulate + add input ----------------
// One wave per output row; lanes own 4 columns each (float4). Row's nnz are
// sorted by column-chunk, so all concurrent waves gather from the same ~2-4 MB
// slice of dense at any time -> per-XCD L2 resident.
__global__ __launch_bounds__(256) void k_spmm(const float4* __restrict__ in4,
                                              const int2* __restrict__ pack,
                                              const int* __restrict__ bstart,
                                              const float4* __restrict__ dense4,
                                              float4* __restrict__ out4) {
    const int wave = threadIdx.x >> 6;
    const int lane = threadIdx.x & 63;
    const int row  = blockIdx.x * 4 + wave;

    int s = bstart[row * CHUNKS];
    int e = bstart[row * CHUNKS + CHUNKS];
    s = __builtin_amdgcn_readfirstlane(s);   // wave-uniform -> scalar loop bounds
    e = __builtin_amdgcn_readfirstlane(e);

    float ax = 0.f, ay = 0.f, az = 0.f, aw = 0.f;

    int i = s;
    // unroll-8: 8 independent float4 gathers in flight per wave
    for (; i + 8 <= e; i += 8) {
        int2 p0 = pack[i + 0], p1 = pack[i + 1], p2 = pack[i + 2], p3 = pack[i + 3];
        int2 p4 = pack[i + 4], p5 = pack[i + 5], p6 = pack[i + 6], p7 = pack[i + 7];
        float4 d0 = dense4[p0.x * NV4 + lane];
        float4 d1 = dense4[p1.x * NV4 + lane];
        float4 d2 = dense4[p2.x * NV4 + lane];
        float4 d3 = dense4[p3.x * NV4 + lane];
        float4 d4 = dense4[p4.x * NV4 + lane];
        float4 d5 = dense4[p5.x * NV4 + lane];
        float4 d6 = dense4[p6.x * NV4 + lane];
        float4 d7 = dense4[p7.x * NV4 + lane];
        float v0 = __int_as_float(p0.y), v1 = __int_as_float(p1.y);
        float v2 = __int_as_float(p2.y), v3 = __int_as_float(p3.y);
        float v4 = __int_as_float(p4.y), v5 = __int_as_float(p5.y);
        float v6 = __int_as_float(p6.y), v7 = __int_as_float(p7.y);
        ax += v0 * d0.x; ay += v0 * d0.y; az += v0 * d0.z; aw += v0 * d0.w;
        ax += v1 * d1.x; ay += v1 * d1.y; az += v1 * d1.z; aw += v1 * d1.w;
        ax += v2 * d2.x; ay += v2 * d2.y; az += v2 * d2.z; aw += v2 * d2.w;
        ax += v3 * d3.x; ay += v3 * d3.y; az += v3 * d3.z; aw += v3 * d3.w;
        ax += v4 * d4.x; ay += v4 * d4.y; az += v4 * d4.z; aw += v4 * d4.w;
        ax += v5 * d5.x; ay += v5 * d5.y; az += v5 * d5.z; aw += v5 * d5.w;
        ax += v6 * d6.x; ay += v6 * d6.y; az += v6 * d6.z; aw += v6 * d6.w;
        ax += v7 * d7.x; ay += v7 * d7.y; az += v7 * d7.z; aw += v7 * d7.w;
    }
    for (; i < e; ++i) {
        int2 p   = pack[i];
        float4 d = dense4[p.x * NV4 + lane];
        float v  = __int_as_float(p.y);
        ax += v * d.x; ay += v * d.y; az += v * d.z; aw += v * d.w;
    }

    const int o = row * NV4 + lane;
    float4 iv = in4[o];
    float4 r;
    r.x = iv.x + ax; r.y = iv.y + ay; r.z = iv.z + az; r.w = iv.w + aw;
    out4[o] = r;
}

// ---------------- Fallback path (if ws too small): copy + atomic scatter ----------------
__global__ void k_copy4(const float4* __restrict__ in4, float4* __restrict__ out4, int n4) {
    int t = blockIdx.x * blockDim.x + threadIdx.x;
    if (t < n4) out4[t] = in4[t];
}

__global__ void k_atomic(const float* __restrict__ values, const int* __restrict__ rows,
                         const int* __restrict__ cols, const float4* __restrict__ dense4,
                         float* __restrict__ out, int nnz) {
    long long t = (long long)blockIdx.x * blockDim.x + threadIdx.x;
    long long total = (long long)nnz * 64;
    if (t >= total) return;
    int i   = (int)(t >> 6);
    int seg = (int)(t & 63);
    float v  = values[i];
    float4 d = dense4[cols[i] * NV4 + seg];
    float* o = out + (size_t)rows[i] * NCOLS + seg * 4;
    atomicAdd(o + 0, v * d.x);
    atomicAdd(o + 1, v * d.y);
    atomicAdd(o + 2, v * d.z);
    atomicAdd(o + 3, v * d.w);
}

extern "C" void kernel_launch(void* const* d_in, const int* in_sizes, int n_in,
                              void* d_out, int out_size, void* d_ws, size_t ws_size,
                              hipStream_t stream) {
    const float* input_mat = (const float*)d_in[0];
    const float* values    = (const float*)d_in[1];
    const int*   rows      = (const int*)d_in[2];
    const int*   cols      = (const int*)d_in[3];
    const float* dense     = (const float*)d_in[4];
    float*       out       = (float*)d_out;

    const int nnz = in_sizes[1];

    // workspace layout: cursor[NB] | bstart[NB+1] | pack[nnz] (int2, 16B-aligned)
    const size_t off_cursor = 0;
    const size_t off_bs     = (size_t)NB * 4;
    size_t off_pack         = off_bs + ((size_t)NB + 1) * 4;
    off_pack                = (off_pack + 255) & ~(size_t)255;
    const size_t need       = off_pack + (size_t)nnz * 8;

    char* ws = (char*)d_ws;

    if (ws_size >= need) {
        int*  cursor = (int*)(ws + off_cursor);
        int*  bstart = (int*)(ws + off_bs);
        int2* pack   = (int2*)(ws + off_pack);

        hipMemsetAsync(cursor, 0, (size_t)NB * 4, stream);
        k_hist<<<(nnz + 255) / 256, 256, 0, stream>>>(rows, cols, cursor, nnz);
        k_scan<<<1, 1024, 0, stream>>>(cursor, bstart, cursor);
        k_scatter<<<(nnz + 255) / 256, 256, 0, stream>>>(values, rows, cols, cursor,
                                                         pack, nnz);
        k_spmm<<<MROWS / 4, 256, 0, stream>>>((const float4*)input_mat, pack, bstart,
                                              (const float4*)dense, (float4*)out);
    } else {
        // fallback: atomic scatter (slow but needs no scratch)
        const int n4 = MROWS * NV4;
        k_copy4<<<(n4 + 255) / 256, 256, 0, stream>>>((const float4*)input_mat,
                                                      (float4*)out, n4);
        long long total = (long long)nnz * 64;
        int blocks = (int)((total + 255) / 256);
        k_atomic<<<blocks, 256, 0, stream>>>(values, rows, cols, (const float4*)dense,
                                             out, nnz);
    }
}

// Round 3
// 188.136 us; speedup vs baseline: 1.5965x; 1.5965x over previous
//
#include <hip/hip_runtime.h>

#define MROWS   16384
#define NCOLS   256
#define NV4     (NCOLS / 4)        // 64 float4 per row
#define CHUNKS  8                  // column chunks: col>>11 -> 2048 rows = 2 MB each
#define CSHIFT  11
#define NB      (MROWS * CHUNKS)   // 131072 buckets

#define SPMM_BLOCKS     1024       // 4 blocks/CU -> all co-resident, lockstep phases
#define ROWS_PER_BLOCK  (MROWS / SPMM_BLOCKS)   // 16
#define ROWS_PER_WAVE   (ROWS_PER_BLOCK / 4)    // 4

// ---------------- K2: histogram of (row, col-chunk) keys ----------------
__global__ void k_hist(const int* __restrict__ rows, const int* __restrict__ cols,
                       int* __restrict__ cnt, int nnz) {
    int t = blockIdx.x * blockDim.x + threadIdx.x;
    if (t < nnz) {
        int key = (rows[t] << 3) | (cols[t] >> CSHIFT);
        atomicAdd(&cnt[key], 1);
    }
}

// ---------------- scan stage 1: coalesced per-block sums (512 blocks x 256) ----------------
__global__ __launch_bounds__(256) void k_scan1(const int* __restrict__ cnt,
                                               int* __restrict__ bsum) {
    __shared__ int sm[256];
    const int t = threadIdx.x;
    sm[t] = cnt[blockIdx.x * 256 + t];
    __syncthreads();
    for (int off = 128; off > 0; off >>= 1) {
        if (t < off) sm[t] += sm[t + off];
        __syncthreads();
    }
    if (t == 0) bsum[blockIdx.x] = sm[0];
}

// ---------------- scan stage 2: 1 block scans the 512 block sums ----------------
__global__ __launch_bounds__(512) void k_scan2(const int* __restrict__ bsum,
                                               int* __restrict__ bpre) {
    __shared__ int sm[512];
    const int t = threadIdx.x;
    int v = bsum[t];
    sm[t] = v;
    __syncthreads();
    for (int off = 1; off < 512; off <<= 1) {
        int u = 0;
        if (t >= off) u = sm[t - off];
        __syncthreads();
        if (t >= off) sm[t] += u;
        __syncthreads();
    }
    bpre[t] = sm[t] - v;                 // exclusive
    if (t == 511) bpre[512] = sm[511];   // total
}

// ---------------- scan stage 3: coalesced final exclusive prefix ----------------
__global__ __launch_bounds__(256) void k_scan3(const int* __restrict__ cnt_in,
                                               const int* __restrict__ bpre,
                                               int* __restrict__ bstart,
                                               int* __restrict__ cursor) {
    __shared__ int sm[256];
    const int t = threadIdx.x;
    const int g = blockIdx.x * 256 + t;
    int v = cnt_in[g];
    sm[t] = v;
    __syncthreads();
    for (int off = 1; off < 256; off <<= 1) {
        int u = 0;
        if (t >= off) u = sm[t - off];
        __syncthreads();
        if (t >= off) sm[t] += u;
        __syncthreads();
    }
    int excl = sm[t] - v + bpre[blockIdx.x];
    bstart[g] = excl;
    cursor[g] = excl;
    if (blockIdx.x == gridDim.x - 1 && t == 255) bstart[NB] = bpre[512];
}

// ---------------- K4: scatter nnz into (row,chunk)-sorted order, packed 8B ----------------
__global__ void k_scatter(const float* __restrict__ values, const int* __restrict__ rows,
                          const int* __restrict__ cols, int* __restrict__ cursor,
                          int2* __restrict__ pack, int nnz) {
    int t = blockIdx.x * blockDim.x + threadIdx.x;
    if (t < nnz) {
        int c   = cols[t];
        int key = (rows[t] << 3) | (c >> CSHIFT);
        int pos = atomicAdd(&cursor[key], 1);
        pack[pos] = make_int2(c, __float_as_int(values[t]));
    }
}

// ---------------- K5: persistent-block chunk-phased gather-accumulate ----------------
// 1024 blocks, all co-resident and started together -> blocks traverse column
// chunks in near-lockstep. blockIdx&7 staggers the phase per XCD (round-robin
// block->XCD mapping), so each XCD's L2 holds one ~2 MB dense slice at a time.
__global__ __launch_bounds__(256, 4) void k_spmm(const float4* __restrict__ in4,
                                                 const int2* __restrict__ pack,
                                                 const int* __restrict__ bstart,
                                                 const float4* __restrict__ dense4,
                                                 float4* __restrict__ out4) {
    const int wave = threadIdx.x >> 6;
    const int lane = threadIdx.x & 63;
    const int rb   = blockIdx.x * ROWS_PER_BLOCK + wave * ROWS_PER_WAVE;
    const int ph0  = blockIdx.x & 7;

    float4 acc[ROWS_PER_WAVE];
#pragma unroll
    for (int r = 0; r < ROWS_PER_WAVE; ++r) acc[r] = make_float4(0.f, 0.f, 0.f, 0.f);

    for (int p = 0; p < CHUNKS; ++p) {
        const int c = (ph0 + p) & 7;
#pragma unroll
        for (int r = 0; r < ROWS_PER_WAVE; ++r) {
            int s = bstart[(rb + r) * CHUNKS + c];
            int e = bstart[(rb + r) * CHUNKS + c + 1];
            s = __builtin_amdgcn_readfirstlane(s);
            e = __builtin_amdgcn_readfirstlane(e);
            int i = s;
            for (; i + 4 <= e; i += 4) {
                int2 q0 = pack[i + 0], q1 = pack[i + 1];
                int2 q2 = pack[i + 2], q3 = pack[i + 3];
                float4 d0 = dense4[q0.x * NV4 + lane];
                float4 d1 = dense4[q1.x * NV4 + lane];
                float4 d2 = dense4[q2.x * NV4 + lane];
                float4 d3 = dense4[q3.x * NV4 + lane];
                float v0 = __int_as_float(q0.y), v1 = __int_as_float(q1.y);
                float v2 = __int_as_float(q2.y), v3 = __int_as_float(q3.y);
                acc[r].x += v0 * d0.x; acc[r].y += v0 * d0.y;
                acc[r].z += v0 * d0.z; acc[r].w += v0 * d0.w;
                acc[r].x += v1 * d1.x; acc[r].y += v1 * d1.y;
                acc[r].z += v1 * d1.z; acc[r].w += v1 * d1.w;
                acc[r].x += v2 * d2.x; acc[r].y += v2 * d2.y;
                acc[r].z += v2 * d2.z; acc[r].w += v2 * d2.w;
                acc[r].x += v3 * d3.x; acc[r].y += v3 * d3.y;
                acc[r].z += v3 * d3.z; acc[r].w += v3 * d3.w;
            }
            for (; i < e; ++i) {
                int2 q   = pack[i];
                float4 d = dense4[q.x * NV4 + lane];
                float v  = __int_as_float(q.y);
                acc[r].x += v * d.x; acc[r].y += v * d.y;
                acc[r].z += v * d.z; acc[r].w += v * d.w;
            }
        }
    }

#pragma unroll
    for (int r = 0; r < ROWS_PER_WAVE; ++r) {
        const int o = (rb + r) * NV4 + lane;
        float4 iv = in4[o];
        out4[o] = make_float4(iv.x + acc[r].x, iv.y + acc[r].y,
                              iv.z + acc[r].z, iv.w + acc[r].w);
    }
}

// ---------------- Fallback path (if ws too small): copy + atomic scatter ----------------
__global__ void k_copy4(const float4* __restrict__ in4, float4* __restrict__ out4, int n4) {
    int t = blockIdx.x * blockDim.x + threadIdx.x;
    if (t < n4) out4[t] = in4[t];
}

__global__ void k_atomic(const float* __restrict__ values, const int* __restrict__ rows,
                         const int* __restrict__ cols, const float4* __restrict__ dense4,
                         float* __restrict__ out, int nnz) {
    long long t = (long long)blockIdx.x * blockDim.x + threadIdx.x;
    long long total = (long long)nnz * 64;
    if (t >= total) return;
    int i   = (int)(t >> 6);
    int seg = (int)(t & 63);
    float v  = values[i];
    float4 d = dense4[cols[i] * NV4 + seg];
    float* o = out + (size_t)rows[i] * NCOLS + seg * 4;
    atomicAdd(o + 0, v * d.x);
    atomicAdd(o + 1, v * d.y);
    atomicAdd(o + 2, v * d.z);
    atomicAdd(o + 3, v * d.w);
}

extern "C" void kernel_launch(void* const* d_in, const int* in_sizes, int n_in,
                              void* d_out, int out_size, void* d_ws, size_t ws_size,
                              hipStream_t stream) {
    const float* input_mat = (const float*)d_in[0];
    const float* values    = (const float*)d_in[1];
    const int*   rows      = (const int*)d_in[2];
    const int*   cols      = (const int*)d_in[3];
    const float* dense     = (const float*)d_in[4];
    float*       out       = (float*)d_out;

    const int nnz = in_sizes[1];

    // ws layout: cursor[NB] | bstart[NB+1] | bsum[512] | bpre[513] | pack[nnz] int2
    const size_t off_cursor = 0;
    const size_t off_bs     = (size_t)NB * 4;
    const size_t off_bsum   = off_bs + ((size_t)NB + 1) * 4;
    const size_t off_bpre   = off_bsum + 512 * 4;
    size_t off_pack         = off_bpre + 513 * 4;
    off_pack                = (off_pack + 255) & ~(size_t)255;
    const size_t need       = off_pack + (size_t)nnz * 8;

    char* ws = (char*)d_ws;

    if (ws_size >= need) {
        int*  cursor = (int*)(ws + off_cursor);
        int*  bstart = (int*)(ws + off_bs);
        int*  bsum   = (int*)(ws + off_bsum);
        int*  bpre   = (int*)(ws + off_bpre);
        int2* pack   = (int2*)(ws + off_pack);

        hipMemsetAsync(cursor, 0, (size_t)NB * 4, stream);
        k_hist<<<(nnz + 255) / 256, 256, 0, stream>>>(rows, cols, cursor, nnz);
        k_scan1<<<NB / 256, 256, 0, stream>>>(cursor, bsum);
        k_scan2<<<1, 512, 0, stream>>>(bsum, bpre);
        k_scan3<<<NB / 256, 256, 0, stream>>>(cursor, bpre, bstart, cursor);
        k_scatter<<<(nnz + 255) / 256, 256, 0, stream>>>(values, rows, cols, cursor,
                                                         pack, nnz);
        k_spmm<<<SPMM_BLOCKS, 256, 0, stream>>>((const float4*)input_mat, pack, bstart,
                                                (const float4*)dense, (float4*)out);
    } else {
        // fallback: atomic scatter (slow but needs no scratch)
        const int n4 = MROWS * NV4;
        k_copy4<<<(n4 + 255) / 256, 256, 0, stream>>>((const float4*)input_mat,
                                                      (float4*)out, n4);
        long long total = (long long)nnz * 64;
        int blocks = (int)((total + 255) / 256);
        k_atomic<<<blocks, 256, 0, stream>>>(values, rows, cols, (const float4*)dense,
                                             out, nnz);
    }
}

// Round 4
// 180.038 us; speedup vs baseline: 1.6683x; 1.0450x over previous
//
#include <hip/hip_runtime.h>

#define MROWS   16384
#define NCOLS   256
#define NV4     (NCOLS / 4)        // 64 float4 per row
#define CHUNKS  8                  // column chunks: col>>11 -> 2048 rows = 2 MB each
#define CSHIFT  11
#define NB      (MROWS * CHUNKS)   // 131072 buckets

// chunk-major key: all rows of one chunk contiguous in pack
__device__ __forceinline__ int mk_key(int r, int c) {
    return ((c >> CSHIFT) << 14) | r;
}

#define SPMM_BLOCKS 2048                       // 8 blocks/CU -> all co-resident
#define RPB (MROWS / SPMM_BLOCKS)              // 8 rows per block
#define RPW (RPB / 4)                          // 2 rows per wave

#define SCAT_BLOCKS 2048

// ---------------- K2: histogram of chunk-major keys ----------------
__global__ void k_hist(const int* __restrict__ rows, const int* __restrict__ cols,
                       int* __restrict__ cnt, int nnz) {
    int t = blockIdx.x * blockDim.x + threadIdx.x;
    if (t < nnz) atomicAdd(&cnt[mk_key(rows[t], cols[t])], 1);
}

// ---------------- scan stage 1: coalesced per-block sums (512 x 256) ----------------
__global__ __launch_bounds__(256) void k_scan1(const int* __restrict__ cnt,
                                               int* __restrict__ bsum) {
    __shared__ int sm[256];
    const int t = threadIdx.x;
    sm[t] = cnt[blockIdx.x * 256 + t];
    __syncthreads();
    for (int off = 128; off > 0; off >>= 1) {
        if (t < off) sm[t] += sm[t + off];
        __syncthreads();
    }
    if (t == 0) bsum[blockIdx.x] = sm[0];
}

// ---------------- scan stage 2: 1 block scans the 512 block sums ----------------
__global__ __launch_bounds__(512) void k_scan2(const int* __restrict__ bsum,
                                               int* __restrict__ bpre) {
    __shared__ int sm[512];
    const int t = threadIdx.x;
    int v = bsum[t];
    sm[t] = v;
    __syncthreads();
    for (int off = 1; off < 512; off <<= 1) {
        int u = 0;
        if (t >= off) u = sm[t - off];
        __syncthreads();
        if (t >= off) sm[t] += u;
        __syncthreads();
    }
    bpre[t] = sm[t] - v;                 // exclusive
    if (t == 511) bpre[512] = sm[511];   // total
}

// ---------------- scan stage 3: coalesced final exclusive prefix ----------------
__global__ __launch_bounds__(256) void k_scan3(const int* __restrict__ cnt_in,
                                               const int* __restrict__ bpre,
                                               int* __restrict__ bstart,
                                               int* __restrict__ cursor) {
    __shared__ int sm[256];
    const int t = threadIdx.x;
    const int g = blockIdx.x * 256 + t;
    int v = cnt_in[g];
    sm[t] = v;
    __syncthreads();
    for (int off = 1; off < 256; off <<= 1) {
        int u = 0;
        if (t >= off) u = sm[t - off];
        __syncthreads();
        if (t >= off) sm[t] += u;
        __syncthreads();
    }
    int excl = sm[t] - v + bpre[blockIdx.x];
    bstart[g] = excl;
    cursor[g] = excl;
    if (blockIdx.x == gridDim.x - 1 && t == 255) bstart[NB] = bpre[512];
}

// ---------------- K4: XCD-filtered scatter ----------------
// Blocks with the same (blockIdx&7) land on the same XCD (round-robin
// heuristic) and handle only nnz whose column-chunk == that filter, so all
// their pack stores target one contiguous ~1 MB region that stays in the
// local L2 and evicts once. Correctness does not depend on the mapping.
__global__ __launch_bounds__(256) void k_scatter(const float* __restrict__ values,
                                                 const int* __restrict__ rows,
                                                 const int* __restrict__ cols,
                                                 int* __restrict__ cursor,
                                                 int2* __restrict__ pack, int nnz) {
    const int f      = blockIdx.x & 7;          // chunk filter
    const int slice  = blockIdx.x >> 3;         // 256 slices
    const int nslice = SCAT_BLOCKS / 8;
    const int per    = (nnz + nslice - 1) / nslice;
    const int begin  = slice * per;
    const int end    = min(begin + per, nnz);
    for (int i = begin + threadIdx.x; i < end; i += 256) {
        int c = cols[i];
        if ((c >> CSHIFT) == f) {
            int r   = rows[i];
            int pos = atomicAdd(&cursor[mk_key(r, c)], 1);
            pack[pos] = make_int2(c, __float_as_int(values[i]));
        }
    }
}

// ---------------- K5: chunk-phased gather-accumulate, full occupancy ----------------
// 2048 co-resident blocks (8/CU), 2 rows per wave. Chunk-major keys make the
// wave's two row-segments contiguous per phase -> one unroll-4 pipeline with a
// wave-uniform 3-way branch routing batches to the right accumulator.
__global__ __launch_bounds__(256, 8) void k_spmm(const float4* __restrict__ in4,
                                                 const int2* __restrict__ pack,
                                                 const int* __restrict__ bstart,
                                                 const float4* __restrict__ dense4,
                                                 float4* __restrict__ out4) {
    const int wave = threadIdx.x >> 6;
    const int lane = threadIdx.x & 63;
    const int rb   = blockIdx.x * RPB + wave * RPW;   // rows rb, rb+1
    const int ph0  = blockIdx.x & 7;

    float4 a0 = make_float4(0.f, 0.f, 0.f, 0.f);
    float4 a1 = make_float4(0.f, 0.f, 0.f, 0.f);

    for (int p = 0; p < CHUNKS; ++p) {
        const int c    = (ph0 + p) & 7;
        const int base = c * MROWS + rb;
        int s  = bstart[base];
        int e0 = bstart[base + 1];
        int e  = bstart[base + 2];
        s  = __builtin_amdgcn_readfirstlane(s);
        e0 = __builtin_amdgcn_readfirstlane(e0);
        e  = __builtin_amdgcn_readfirstlane(e);

        int i = s;
        for (; i + 4 <= e; i += 4) {
            int2 q0 = pack[i + 0], q1 = pack[i + 1];
            int2 q2 = pack[i + 2], q3 = pack[i + 3];
            float4 d0 = dense4[q0.x * NV4 + lane];
            float4 d1 = dense4[q1.x * NV4 + lane];
            float4 d2 = dense4[q2.x * NV4 + lane];
            float4 d3 = dense4[q3.x * NV4 + lane];
            float v0 = __int_as_float(q0.y), v1 = __int_as_float(q1.y);
            float v2 = __int_as_float(q2.y), v3 = __int_as_float(q3.y);
            if (i + 3 < e0) {            // whole batch -> row0 (uniform branch)
                a0.x += v0 * d0.x; a0.y += v0 * d0.y; a0.z += v0 * d0.z; a0.w += v0 * d0.w;
                a0.x += v1 * d1.x; a0.y += v1 * d1.y; a0.z += v1 * d1.z; a0.w += v1 * d1.w;
                a0.x += v2 * d2.x; a0.y += v2 * d2.y; a0.z += v2 * d2.z; a0.w += v2 * d2.w;
                a0.x += v3 * d3.x; a0.y += v3 * d3.y; a0.z += v3 * d3.z; a0.w += v3 * d3.w;
            } else if (i >= e0) {        // whole batch -> row1
                a1.x += v0 * d0.x; a1.y += v0 * d0.y; a1.z += v0 * d0.z; a1.w += v0 * d0.w;
                a1.x += v1 * d1.x; a1.y += v1 * d1.y; a1.z += v1 * d1.z; a1.w += v1 * d1.w;
                a1.x += v2 * d2.x; a1.y += v2 * d2.y; a1.z += v2 * d2.z; a1.w += v2 * d2.w;
                a1.x += v3 * d3.x; a1.y += v3 * d3.y; a1.z += v3 * d3.z; a1.w += v3 * d3.w;
            } else {                     // boundary batch: mask-route (<=1 per phase)
                float w00 = (i + 0 < e0) ? v0 : 0.f, w10 = v0 - w00;
                float w01 = (i + 1 < e0) ? v1 : 0.f, w11 = v1 - w01;
                float w02 = (i + 2 < e0) ? v2 : 0.f, w12 = v2 - w02;
                float w03 = (i + 3 < e0) ? v3 : 0.f, w13 = v3 - w03;
                a0.x += w00 * d0.x; a0.y += w00 * d0.y; a0.z += w00 * d0.z; a0.w += w00 * d0.w;
                a1.x += w10 * d0.x; a1.y += w10 * d0.y; a1.z += w10 * d0.z; a1.w += w10 * d0.w;
                a0.x += w01 * d1.x; a0.y += w01 * d1.y; a0.z += w01 * d1.z; a0.w += w01 * d1.w;
                a1.x += w11 * d1.x; a1.y += w11 * d1.y; a1.z += w11 * d1.z; a1.w += w11 * d1.w;
                a0.x += w02 * d2.x; a0.y += w02 * d2.y; a0.z += w02 * d2.z; a0.w += w02 * d2.w;
                a1.x += w12 * d2.x; a1.y += w12 * d2.y; a1.z += w12 * d2.z; a1.w += w12 * d2.w;
                a0.x += w03 * d3.x; a0.y += w03 * d3.y; a0.z += w03 * d3.z; a0.w += w03 * d3.w;
                a1.x += w13 * d3.x; a1.y += w13 * d3.y; a1.z += w13 * d3.z; a1.w += w13 * d3.w;
            }
        }
        for (; i < e; ++i) {
            int2 q   = pack[i];
            float4 d = dense4[q.x * NV4 + lane];
            float v  = __int_as_float(q.y);
            if (i < e0) {
                a0.x += v * d.x; a0.y += v * d.y; a0.z += v * d.z; a0.w += v * d.w;
            } else {
                a1.x += v * d.x; a1.y += v * d.y; a1.z += v * d.z; a1.w += v * d.w;
            }
        }
    }

    int o = rb * NV4 + lane;
    float4 iv = in4[o];
    out4[o] = make_float4(iv.x + a0.x, iv.y + a0.y, iv.z + a0.z, iv.w + a0.w);
    o += NV4;
    iv = in4[o];
    out4[o] = make_float4(iv.x + a1.x, iv.y + a1.y, iv.z + a1.z, iv.w + a1.w);
}

// ---------------- Fallback path (if ws too small): copy + atomic scatter ----------------
__global__ void k_copy4(const float4* __restrict__ in4, float4* __restrict__ out4, int n4) {
    int t = blockIdx.x * blockDim.x + threadIdx.x;
    if (t < n4) out4[t] = in4[t];
}

__global__ void k_atomic(const float* __restrict__ values, const int* __restrict__ rows,
                         const int* __restrict__ cols, const float4* __restrict__ dense4,
                         float* __restrict__ out, int nnz) {
    long long t = (long long)blockIdx.x * blockDim.x + threadIdx.x;
    long long total = (long long)nnz * 64;
    if (t >= total) return;
    int i   = (int)(t >> 6);
    int seg = (int)(t & 63);
    float v  = values[i];
    float4 d = dense4[cols[i] * NV4 + seg];
    float* o = out + (size_t)rows[i] * NCOLS + seg * 4;
    atomicAdd(o + 0, v * d.x);
    atomicAdd(o + 1, v * d.y);
    atomicAdd(o + 2, v * d.z);
    atomicAdd(o + 3, v * d.w);
}

extern "C" void kernel_launch(void* const* d_in, const int* in_sizes, int n_in,
                              void* d_out, int out_size, void* d_ws, size_t ws_size,
                              hipStream_t stream) {
    const float* input_mat = (const float*)d_in[0];
    const float* values    = (const float*)d_in[1];
    const int*   rows      = (const int*)d_in[2];
    const int*   cols      = (const int*)d_in[3];
    const float* dense     = (const float*)d_in[4];
    float*       out       = (float*)d_out;

    const int nnz = in_sizes[1];

    // ws layout: cursor[NB] | bstart[NB+1] | bsum[512] | bpre[513] | pack[nnz] int2
    const size_t off_cursor = 0;
    const size_t off_bs     = (size_t)NB * 4;
    const size_t off_bsum   = off_bs + ((size_t)NB + 1) * 4;
    const size_t off_bpre   = off_bsum + 512 * 4;
    size_t off_pack         = off_bpre + 513 * 4;
    off_pack                = (off_pack + 255) & ~(size_t)255;
    const size_t need       = off_pack + (size_t)nnz * 8;

    char* ws = (char*)d_ws;

    if (ws_size >= need) {
        int*  cursor = (int*)(ws + off_cursor);
        int*  bstart = (int*)(ws + off_bs);
        int*  bsum   = (int*)(ws + off_bsum);
        int*  bpre   = (int*)(ws + off_bpre);
        int2* pack   = (int2*)(ws + off_pack);

        hipMemsetAsync(cursor, 0, (size_t)NB * 4, stream);
        k_hist<<<(nnz + 255) / 256, 256, 0, stream>>>(rows, cols, cursor, nnz);
        k_scan1<<<NB / 256, 256, 0, stream>>>(cursor, bsum);
        k_scan2<<<1, 512, 0, stream>>>(bsum, bpre);
        k_scan3<<<NB / 256, 256, 0, stream>>>(cursor, bpre, bstart, cursor);
        k_scatter<<<SCAT_BLOCKS, 256, 0, stream>>>(values, rows, cols, cursor,
                                                   pack, nnz);
        k_spmm<<<SPMM_BLOCKS, 256, 0, stream>>>((const float4*)input_mat, pack, bstart,
                                                (const float4*)dense, (float4*)out);
    } else {
        // fallback: atomic scatter (slow but needs no scratch)
        const int n4 = MROWS * NV4;
        k_copy4<<<(n4 + 255) / 256, 256, 0, stream>>>((const float4*)input_mat,
                                                      (float4*)out, n4);
        long long total = (long long)nnz * 64;
        int blocks = (int)((total + 255) / 256);
        k_atomic<<<blocks, 256, 0, stream>>>(values, rows, cols, (const float4*)dense,
                                             out, nnz);
    }
}